// Round 1
// baseline (1109.285 us; speedup 1.0000x reference)
//
#include <hip/hip_runtime.h>

#define T_SEQ 2048
#define NB    2
#define NH    32
#define NKV   8
#define HD    128
#define DIM   4096
#define EDIM  6144
#define M_TOK 4096   // NB*T_SEQ

typedef __bf16          bf8 __attribute__((ext_vector_type(8)));
typedef unsigned short  us8 __attribute__((ext_vector_type(8)));
typedef float           f4  __attribute__((ext_vector_type(4)));

__device__ inline unsigned short f2bf(float f) {
  unsigned int u = __builtin_bit_cast(unsigned int, f);
  u += 0x7FFF + ((u >> 16) & 1);              // round-to-nearest-even
  return (unsigned short)(u >> 16);
}
__device__ inline float bf2f(unsigned short h) {
  unsigned int u = ((unsigned int)h) << 16;
  return __builtin_bit_cast(float, u);
}
__device__ inline void gl_lds16(const void* g, void* l) {
  __builtin_amdgcn_global_load_lds(
      (const __attribute__((address_space(1))) unsigned int*)g,
      (__attribute__((address_space(3))) unsigned int*)l, 16, 0, 0);
}
__device__ inline f4 mfma16(bf8 a, bf8 b, f4 c) {
  return __builtin_amdgcn_mfma_f32_16x16x32_bf16(a, b, c, 0, 0, 0);
}

// ---------------- f32 -> bf16 conversion ----------------
__global__ void k_f2bf(const float* __restrict__ in, unsigned short* __restrict__ out, int n4) {
  int i = blockIdx.x * blockDim.x + threadIdx.x;
  if (i >= n4) return;
  f4 v = *(const f4*)(in + (size_t)i * 4);
  unsigned long long pack =
      (unsigned long long)f2bf(v[0]) |
      ((unsigned long long)f2bf(v[1]) << 16) |
      ((unsigned long long)f2bf(v[2]) << 32) |
      ((unsigned long long)f2bf(v[3]) << 48);
  *(unsigned long long*)(out + (size_t)i * 4) = pack;
}

// ---------------- GEMM: C[m,n] = sum_k A[m,k]*B[n,k] (both row-major, B^T layout) ----
// MODE 0: bf16 out, split into Q/K/V regions by column. MODE 1: f32 out.
template <int MODE>
__global__ __launch_bounds__(256)
void k_gemm(const unsigned short* __restrict__ A, const unsigned short* __restrict__ Bm,
            int M, int N, int K,
            unsigned short* __restrict__ oQ, unsigned short* __restrict__ oK,
            unsigned short* __restrict__ oV, float* __restrict__ oF) {
  __shared__ unsigned short As[128 * 64];
  __shared__ unsigned short Bs[128 * 64];
  const int bn = blockIdx.x, bm = blockIdx.y;
  const int t = threadIdx.x;
  const int lane = t & 63, w = t >> 6;
  const int wr = w >> 1, wc = w & 1;
  const int l15 = lane & 15, lhi = lane >> 4;
  f4 acc[4][4] = {};
  int aoff[4], boff[4];
#pragma unroll
  for (int m = 0; m < 4; ++m) aoff[m] = (wr * 64 + m * 16 + l15) * 64 + lhi * 8;
#pragma unroll
  for (int n = 0; n < 4; ++n) boff[n] = (wc * 64 + n * 16 + l15) * 64 + lhi * 8;
  const int e0 = t * 8;
  for (int kt = 0; kt < K; kt += 64) {
#pragma unroll
    for (int i = 0; i < 4; ++i) {
      int e = i * 2048 + e0;
      int r = e >> 6, c = e & 63;
      gl_lds16(A  + (size_t)(bm * 128 + r) * K + kt + c, &As[e]);
      gl_lds16(Bm + (size_t)(bn * 128 + r) * K + kt + c, &Bs[e]);
    }
    __syncthreads();
#pragma unroll
    for (int kk = 0; kk < 2; ++kk) {
      bf8 af[4], bfr[4];
#pragma unroll
      for (int m = 0; m < 4; ++m)
        af[m] = __builtin_bit_cast(bf8, *(const us8*)&As[aoff[m] + kk * 32]);
#pragma unroll
      for (int n = 0; n < 4; ++n)
        bfr[n] = __builtin_bit_cast(bf8, *(const us8*)&Bs[boff[n] + kk * 32]);
#pragma unroll
      for (int m = 0; m < 4; ++m)
#pragma unroll
        for (int n = 0; n < 4; ++n)
          acc[m][n] = mfma16(af[m], bfr[n], acc[m][n]);
    }
    __syncthreads();
  }
  const int rbase = bm * 128 + wr * 64;
  const int cbase = bn * 128 + wc * 64;
  if (MODE == 0) {
    unsigned short* op; int ldo, c0;
    if (cbase < 4096)      { op = oQ; ldo = 4096; c0 = cbase; }
    else if (cbase < 5120) { op = oK; ldo = 1024; c0 = cbase - 4096; }
    else                   { op = oV; ldo = 1024; c0 = cbase - 5120; }
#pragma unroll
    for (int m = 0; m < 4; ++m)
#pragma unroll
      for (int n = 0; n < 4; ++n)
#pragma unroll
        for (int r = 0; r < 4; ++r) {
          int row = rbase + m * 16 + lhi * 4 + r;
          int col = c0 + n * 16 + l15;
          op[(size_t)row * ldo + col] = f2bf(acc[m][n][r]);
        }
  } else {
#pragma unroll
    for (int m = 0; m < 4; ++m)
#pragma unroll
      for (int n = 0; n < 4; ++n)
#pragma unroll
        for (int r = 0; r < 4; ++r) {
          int row = rbase + m * 16 + lhi * 4 + r;
          int col = cbase + n * 16 + l15;
          oF[(size_t)row * N + col] = acc[m][n][r];
        }
  }
}

// ---------------- RoPE in-place on Qb and Kb (interleaved pairs) ----------------
__global__ void k_rope(unsigned short* __restrict__ Qb, unsigned short* __restrict__ Kb,
                       const float* __restrict__ cosp, const float* __restrict__ sinp) {
  int idx = blockIdx.x * blockDim.x + threadIdx.x;
  const int nq = M_TOK * NH * 16;   // each thread: 4 pairs = 8 bf16
  const int nk = M_TOK * NKV * 16;
  unsigned short* p; int tpos, pg;
  if (idx < nq) {
    int m = idx >> 9;        // /(NH*16)
    int r = idx & 511;
    int h = r >> 4; pg = r & 15;
    tpos = m & (T_SEQ - 1);
    p = Qb + (size_t)m * 4096 + h * 128 + pg * 8;
  } else {
    idx -= nq;
    if (idx >= nk) return;
    int m = idx >> 7;        // /(NKV*16)
    int r = idx & 127;
    int h = r >> 4; pg = r & 15;
    tpos = m & (T_SEQ - 1);
    p = Kb + (size_t)m * 1024 + h * 128 + pg * 8;
  }
  us8 v = *(const us8*)p;
  f4 c = *(const f4*)(cosp + tpos * 64 + pg * 4);
  f4 s = *(const f4*)(sinp + tpos * 64 + pg * 4);
  us8 o;
#pragma unroll
  for (int j = 0; j < 4; ++j) {
    float tr = bf2f(v[2 * j]), ti = bf2f(v[2 * j + 1]);
    o[2 * j]     = f2bf(tr * c[j] - ti * s[j]);
    o[2 * j + 1] = f2bf(tr * s[j] + ti * c[j]);
  }
  *(us8*)p = o;
}

// ---------------- Flash attention, causal, GQA ----------------
// grid: (T/64, NH, NB), 256 threads (4 waves, 16 q-rows each), KVBLK=64
__device__ inline int vswz(int d, int k) {          // V^T LDS offset, 2-way max conflicts
  return d * 64 + (k ^ ((((d >> 3) ^ d) & 7) << 3));
}
__global__ __launch_bounds__(256)
void k_attn(const unsigned short* __restrict__ Qb, const unsigned short* __restrict__ Kb,
            const unsigned short* __restrict__ Vb, unsigned short* __restrict__ Yb) {
  __shared__ unsigned short Vt[128 * 64];
  __shared__ unsigned short Pl[4][16 * 64];
  const int qt = blockIdx.x, h = blockIdx.y, b = blockIdx.z;
  const int kvh = h >> 2;
  const int t = threadIdx.x, lane = t & 63, w = t >> 6;
  const int l15 = lane & 15, lhi = lane >> 4;
  const int qbase = qt * 64 + w * 16;
  const float SCALE = 0.08838834764831845f;
  const float NEG = -__builtin_inff();

  bf8 qf[4];
  {
    const unsigned short* qp = Qb + (size_t)(b * T_SEQ + qbase + l15) * 4096 + h * 128 + lhi * 8;
#pragma unroll
    for (int d = 0; d < 4; ++d) qf[d] = __builtin_bit_cast(bf8, *(const us8*)(qp + d * 32));
  }
  float m_run[4] = {NEG, NEG, NEG, NEG};
  float l_run[4] = {0.f, 0.f, 0.f, 0.f};
  f4 yacc[8] = {};

  for (int kb = 0; kb <= qt; ++kb) {
    const int kbase = kb * 64;
    __syncthreads();                 // protect Vt from previous iteration's readers
    // stage V transposed (Vt[d][k]) with XOR swizzle
#pragma unroll
    for (int i = 0; i < 4; ++i) {
      int c = t + i * 256;
      int kk = c >> 4;
      int dc = (c & 15) * 8;
      us8 vv = *(const us8*)(Vb + (size_t)(b * T_SEQ + kbase + kk) * 1024 + kvh * 128 + dc);
#pragma unroll
      for (int j = 0; j < 8; ++j) Vt[vswz(dc + j, kk)] = vv[j];
    }
    __syncthreads();
    // QK^T : S[16 q][64 k]
    f4 sacc[4] = {};
#pragma unroll
    for (int ct = 0; ct < 4; ++ct) {
      const unsigned short* kp =
          Kb + (size_t)(b * T_SEQ + kbase + ct * 16 + l15) * 1024 + kvh * 128 + lhi * 8;
#pragma unroll
      for (int ds = 0; ds < 4; ++ds) {
        bf8 kf = __builtin_bit_cast(bf8, *(const us8*)(kp + ds * 32));
        sacc[ct] = mfma16(qf[ds], kf, sacc[ct]);
      }
    }
    // scale + causal mask + online softmax
    float tmax[4] = {NEG, NEG, NEG, NEG};
#pragma unroll
    for (int ct = 0; ct < 4; ++ct)
#pragma unroll
      for (int r = 0; r < 4; ++r) {
        int colg = kbase + ct * 16 + l15;
        int rowg = qbase + lhi * 4 + r;
        float sv = sacc[ct][r] * SCALE;
        sv = (colg <= rowg) ? sv : NEG;
        sacc[ct][r] = sv;
        tmax[r] = fmaxf(tmax[r], sv);
      }
#pragma unroll
    for (int r = 0; r < 4; ++r)
#pragma unroll
      for (int off = 1; off < 16; off <<= 1)
        tmax[r] = fmaxf(tmax[r], __shfl_xor(tmax[r], off));
    float fac[4], psum[4];
#pragma unroll
    for (int r = 0; r < 4; ++r) {
      float nm = fmaxf(m_run[r], tmax[r]);
      fac[r] = __expf(m_run[r] - nm);
      m_run[r] = nm;
      psum[r] = 0.f;
    }
#pragma unroll
    for (int ct = 0; ct < 4; ++ct)
#pragma unroll
      for (int r = 0; r < 4; ++r) {
        float pv = __expf(sacc[ct][r] - m_run[r]);
        psum[r] += pv;
        int row = lhi * 4 + r, col = ct * 16 + l15;
        Pl[w][row * 64 + (col ^ ((row & 7) << 3))] = f2bf(pv);
      }
#pragma unroll
    for (int r = 0; r < 4; ++r) {
#pragma unroll
      for (int off = 1; off < 16; off <<= 1)
        psum[r] += __shfl_xor(psum[r], off);
      l_run[r] = l_run[r] * fac[r] + psum[r];
#pragma unroll
      for (int dt = 0; dt < 8; ++dt) yacc[dt][r] *= fac[r];
    }
    __syncthreads();                 // P visible (and Vt staged) for all lanes
    // PV : Y[16 q][128 d] += P[16][64] * V[64][128]
#pragma unroll
    for (int ks = 0; ks < 2; ++ks) {
      int k0 = ks * 32 + lhi * 8;
      bf8 pf = __builtin_bit_cast(bf8,
          *(const us8*)&Pl[w][l15 * 64 + (k0 ^ ((l15 & 7) << 3))]);
#pragma unroll
      for (int dt = 0; dt < 8; ++dt) {
        int d = dt * 16 + l15;
        bf8 vf = __builtin_bit_cast(bf8, *(const us8*)&Vt[vswz(d, k0)]);
        yacc[dt] = mfma16(pf, vf, yacc[dt]);
      }
    }
  }
  // epilogue: y = Y / l
#pragma unroll
  for (int r = 0; r < 4; ++r) {
    float inv = 1.0f / l_run[r];
    int row = qbase + lhi * 4 + r;
#pragma unroll
    for (int dt = 0; dt < 8; ++dt)
      Yb[(size_t)(b * T_SEQ + row) * 4096 + h * 128 + dt * 16 + l15] =
          f2bf(yacc[dt][r] * inv);
  }
}

extern "C" void kernel_launch(void* const* d_in, const int* in_sizes, int n_in,
                              void* d_out, int out_size, void* d_ws, size_t ws_size,
                              hipStream_t stream) {
  const float* x    = (const float*)d_in[0];
  // d_in[1] = freqs_cis (unused by the reference computation)
  const float* wqkv = (const float*)d_in[2];
  const float* wo   = (const float*)d_in[3];
  const float* cosp = (const float*)d_in[4];
  const float* sinp = (const float*)d_in[5];
  float* out = (float*)d_out;

  char* ws = (char*)d_ws;
  size_t o = 0;
  auto alloc = [&](size_t bytes) { void* p = ws + o; o += (bytes + 255) & ~(size_t)255; return p; };
  unsigned short* x_b    = (unsigned short*)alloc((size_t)M_TOK * DIM * 2);
  unsigned short* wqkv_b = (unsigned short*)alloc((size_t)EDIM * DIM * 2);
  unsigned short* wo_b   = (unsigned short*)alloc((size_t)DIM * DIM * 2);
  unsigned short* Qb     = (unsigned short*)alloc((size_t)M_TOK * 4096 * 2);
  unsigned short* Kb     = (unsigned short*)alloc((size_t)M_TOK * 1024 * 2);
  unsigned short* Vb     = (unsigned short*)alloc((size_t)M_TOK * 1024 * 2);
  unsigned short* Yb     = (unsigned short*)alloc((size_t)M_TOK * 4096 * 2);
  if (o > ws_size) return;  // workspace too small: fail visibly (zero output)

  k_f2bf<<<(M_TOK * DIM / 4 + 255) / 256, 256, 0, stream>>>(x, x_b, M_TOK * DIM / 4);
  k_f2bf<<<(EDIM * DIM / 4 + 255) / 256, 256, 0, stream>>>(wqkv, wqkv_b, EDIM * DIM / 4);
  k_f2bf<<<(DIM * DIM / 4 + 255) / 256, 256, 0, stream>>>(wo, wo_b, DIM * DIM / 4);

  k_gemm<0><<<dim3(EDIM / 128, M_TOK / 128), 256, 0, stream>>>(
      x_b, wqkv_b, M_TOK, EDIM, DIM, Qb, Kb, Vb, nullptr);

  k_rope<<<(M_TOK * NH * 16 + M_TOK * NKV * 16 + 255) / 256, 256, 0, stream>>>(
      Qb, Kb, cosp, sinp);

  k_attn<<<dim3(T_SEQ / 64, NH, NB), 256, 0, stream>>>(Qb, Kb, Vb, Yb);

  k_gemm<1><<<dim3(DIM / 128, M_TOK / 128), 256, 0, stream>>>(
      Yb, wo_b, M_TOK, DIM, DIM, nullptr, nullptr, nullptr, out);
}

// Round 3
// 691.796 us; speedup vs baseline: 1.6035x; 1.6035x over previous
//
#include <hip/hip_runtime.h>

#define T_SEQ 2048
#define NB    2
#define NH    32
#define NKV   8
#define HD    128
#define DIM   4096
#define EDIM  6144
#define M_TOK 4096   // NB*T_SEQ

typedef __bf16          bf8  __attribute__((ext_vector_type(8)));
typedef unsigned short  us8  __attribute__((ext_vector_type(8)));
typedef float           f4   __attribute__((ext_vector_type(4)));
typedef float           f16v __attribute__((ext_vector_type(16)));
typedef int             i4   __attribute__((ext_vector_type(4)));

__device__ inline unsigned short f2bf(float f) {
  unsigned int u = __builtin_bit_cast(unsigned int, f);
  u += 0x7FFF + ((u >> 16) & 1);              // round-to-nearest-even
  return (unsigned short)(u >> 16);
}
__device__ inline float bf2f(unsigned short h) {
  unsigned int u = ((unsigned int)h) << 16;
  return __builtin_bit_cast(float, u);
}
__device__ inline void gl_lds16(const void* g, void* l) {
  __builtin_amdgcn_global_load_lds(
      (const __attribute__((address_space(1))) unsigned int*)g,
      (__attribute__((address_space(3))) unsigned int*)l, 16, 0, 0);
}
__device__ inline f4 mfma16(bf8 a, bf8 b, f4 c) {
  return __builtin_amdgcn_mfma_f32_16x16x32_bf16(a, b, c, 0, 0, 0);
}
__device__ inline f16v mfma32(bf8 a, bf8 b, f16v c) {
  return __builtin_amdgcn_mfma_f32_32x32x16_bf16(a, b, c, 0, 0, 0);
}
__device__ inline unsigned cvtpk(float lo, float hi) {
  unsigned r;
  asm("v_cvt_pk_bf16_f32 %0, %1, %2" : "=v"(r) : "v"(lo), "v"(hi));
  return r;
}

// ---------------- f32 -> bf16 conversion ----------------
__global__ void k_f2bf(const float* __restrict__ in, unsigned short* __restrict__ out, int n4) {
  int i = blockIdx.x * blockDim.x + threadIdx.x;
  if (i >= n4) return;
  f4 v = *(const f4*)(in + (size_t)i * 4);
  unsigned long long pack =
      (unsigned long long)f2bf(v[0]) |
      ((unsigned long long)f2bf(v[1]) << 16) |
      ((unsigned long long)f2bf(v[2]) << 32) |
      ((unsigned long long)f2bf(v[3]) << 48);
  *(unsigned long long*)(out + (size_t)i * 4) = pack;
}

// ---------------- GEMM: C[m,n] = sum_k A[m,k]*B[n,k] (both row-major, B^T layout) ----
template <int MODE>
__global__ __launch_bounds__(256)
void k_gemm(const unsigned short* __restrict__ A, const unsigned short* __restrict__ Bm,
            int M, int N, int K,
            unsigned short* __restrict__ oQ, unsigned short* __restrict__ oK,
            unsigned short* __restrict__ oV, float* __restrict__ oF) {
  __shared__ unsigned short As[128 * 64];
  __shared__ unsigned short Bs[128 * 64];
  const int bn = blockIdx.x, bm = blockIdx.y;
  const int t = threadIdx.x;
  const int lane = t & 63, w = t >> 6;
  const int wr = w >> 1, wc = w & 1;
  const int l15 = lane & 15, lhi = lane >> 4;
  f4 acc[4][4] = {};
  int aoff[4], boff[4];
#pragma unroll
  for (int m = 0; m < 4; ++m) aoff[m] = (wr * 64 + m * 16 + l15) * 64 + lhi * 8;
#pragma unroll
  for (int n = 0; n < 4; ++n) boff[n] = (wc * 64 + n * 16 + l15) * 64 + lhi * 8;
  const int e0 = t * 8;
  for (int kt = 0; kt < K; kt += 64) {
#pragma unroll
    for (int i = 0; i < 4; ++i) {
      int e = i * 2048 + e0;
      int r = e >> 6, c = e & 63;
      gl_lds16(A  + (size_t)(bm * 128 + r) * K + kt + c, &As[e]);
      gl_lds16(Bm + (size_t)(bn * 128 + r) * K + kt + c, &Bs[e]);
    }
    __syncthreads();
#pragma unroll
    for (int kk = 0; kk < 2; ++kk) {
      bf8 af[4], bfr[4];
#pragma unroll
      for (int m = 0; m < 4; ++m)
        af[m] = __builtin_bit_cast(bf8, *(const us8*)&As[aoff[m] + kk * 32]);
#pragma unroll
      for (int n = 0; n < 4; ++n)
        bfr[n] = __builtin_bit_cast(bf8, *(const us8*)&Bs[boff[n] + kk * 32]);
#pragma unroll
      for (int m = 0; m < 4; ++m)
#pragma unroll
        for (int n = 0; n < 4; ++n)
          acc[m][n] = mfma16(af[m], bfr[n], acc[m][n]);
    }
    __syncthreads();
  }
  const int rbase = bm * 128 + wr * 64;
  const int cbase = bn * 128 + wc * 64;
  if (MODE == 0) {
    unsigned short* op; int ldo, c0;
    if (cbase < 4096)      { op = oQ; ldo = 4096; c0 = cbase; }
    else if (cbase < 5120) { op = oK; ldo = 1024; c0 = cbase - 4096; }
    else                   { op = oV; ldo = 1024; c0 = cbase - 5120; }
#pragma unroll
    for (int m = 0; m < 4; ++m)
#pragma unroll
      for (int n = 0; n < 4; ++n)
#pragma unroll
        for (int r = 0; r < 4; ++r) {
          int row = rbase + m * 16 + lhi * 4 + r;
          int col = c0 + n * 16 + l15;
          op[(size_t)row * ldo + col] = f2bf(acc[m][n][r]);
        }
  } else {
#pragma unroll
    for (int m = 0; m < 4; ++m)
#pragma unroll
      for (int n = 0; n < 4; ++n)
#pragma unroll
        for (int r = 0; r < 4; ++r) {
          int row = rbase + m * 16 + lhi * 4 + r;
          int col = cbase + n * 16 + l15;
          oF[(size_t)row * N + col] = acc[m][n][r];
        }
  }
}

// ---------------- RoPE in-place; Q additionally scaled by SCALE*log2(e) ----------------
__global__ void k_rope(unsigned short* __restrict__ Qb, unsigned short* __restrict__ Kb,
                       const float* __restrict__ cosp, const float* __restrict__ sinp) {
  const float QSCALE = (float)(0.08838834764831845 * 1.4426950408889634);
  int idx = blockIdx.x * blockDim.x + threadIdx.x;
  const int nq = M_TOK * NH * 16;   // each thread: 4 pairs = 8 bf16
  const int nk = M_TOK * NKV * 16;
  unsigned short* p; int tpos, pg; float sc;
  if (idx < nq) {
    int m = idx >> 9;
    int r = idx & 511;
    int h = r >> 4; pg = r & 15;
    tpos = m & (T_SEQ - 1);
    p = Qb + (size_t)m * 4096 + h * 128 + pg * 8;
    sc = QSCALE;
  } else {
    idx -= nq;
    if (idx >= nk) return;
    int m = idx >> 7;
    int r = idx & 127;
    int h = r >> 4; pg = r & 15;
    tpos = m & (T_SEQ - 1);
    p = Kb + (size_t)m * 1024 + h * 128 + pg * 8;
    sc = 1.0f;
  }
  us8 v = *(const us8*)p;
  f4 c = *(const f4*)(cosp + tpos * 64 + pg * 4);
  f4 s = *(const f4*)(sinp + tpos * 64 + pg * 4);
  us8 o;
#pragma unroll
  for (int j = 0; j < 4; ++j) {
    float cs = c[j] * sc, ss = s[j] * sc;
    float tr = bf2f(v[2 * j]), ti = bf2f(v[2 * j + 1]);
    o[2 * j]     = f2bf(tr * cs - ti * ss);
    o[2 * j + 1] = f2bf(tr * ss + ti * cs);
  }
  *(us8*)p = o;
}

// ---------------- Flash attention v3: 8 waves x 32 q-rows, 32x32x16 MFMA ----------------
// Swapped QK^T: S^T[kv][q] = mfma(A=K, B=Q). C/D layout: col(=q)=lane&31,
// row(=kv)=(reg&3)+8*(reg>>2)+4*(lane>>5). Per-q softmax stats live at lane q=l31;
// the PV accumulator's rows are q_local=crow(r,hh), so BOTH the per-tile rescale
// factor and the final 1/l must be broadcast via shfl to the C/D row layout.
// (v2 bug: rescale used lane-local fac -> wrong q. Fixed here.)
__global__ __launch_bounds__(512, 2)
void k_attn(const unsigned short* __restrict__ Qb, const unsigned short* __restrict__ Kb,
            const unsigned short* __restrict__ Vb, unsigned short* __restrict__ Yb) {
  __shared__ unsigned short Ks[64 * 128];
  __shared__ unsigned short Vt[128 * 64];
  const int idx = blockIdx.x;
  const int qblk = 7 - (idx >> 6);          // heavy blocks dispatched first
  const int h = (idx & 63) >> 1;
  const int b = idx & 1;
  const int kvh = h >> 2;
  const int t = threadIdx.x;
  const int lane = t & 63, w = t >> 6;
  const int l31 = lane & 31, hh = lane >> 5;
  const int qb0 = qblk * 256;
  const int NT = (qblk + 1) * 4;
  const int wqmin = qb0 + w * 32;
  const int q_g = wqmin + l31;              // this lane's q row (S/P layout)
  const float BNEG = -1.0e30f;

  // Q fragments (pre-scaled by SCALE*log2e in k_rope): qf[st] = Q[q_g][st*16+hh*8 ..+8]
  bf8 qf[8];
  {
    const unsigned short* qp = Qb + (size_t)(b * T_SEQ + q_g) * 4096 + h * 128 + hh * 8;
#pragma unroll
    for (int st = 0; st < 8; ++st) qf[st] = __builtin_bit_cast(bf8, *(const us8*)(qp + st * 16));
  }
  const int swz = (l31 & 7) << 3;           // element-unit XOR swizzle (bits 3..5)
  float m_run = BNEG, l_run = 0.f;
  f16v yacc[4] = {};

  const int eo0 = t * 8;                    // K staging: dest elements [i*4096+t*8, +8)
  for (int kt = 0; kt < NT; ++kt) {
    const int kbase = kt * 64;
    // hoisted V loads (global -> reg), land during the barrier wait
    const unsigned short* vp = Vb + (size_t)(b * T_SEQ + kbase + lane) * 1024 + kvh * 128 + w * 8;
    us8 vv0 = *(const us8*)vp;
    us8 vv1 = *(const us8*)(vp + 64);
    __syncthreads();                        // prev tile's LDS reads done
    // K: global_load_lds with pre-swizzled global source, linear LDS dest
#pragma unroll
    for (int i = 0; i < 2; ++i) {
      int eo = i * 4096 + eo0;
      int row = eo >> 7;
      int colL = (eo & 127) ^ ((row & 7) << 3);
      gl_lds16(Kb + (size_t)(b * T_SEQ + kbase + row) * 1024 + kvh * 128 + colL, &Ks[eo]);
    }
    // V: transpose-scatter into swizzled Vt (64 lanes consecutive kv -> conflict-free)
#pragma unroll
    for (int j = 0; j < 8; ++j) {
      int d0 = w * 8 + j;
      Vt[(d0 * 64 + lane) ^ ((d0 & 7) << 3)] = vv0[j];
      int d1 = d0 + 64;
      Vt[(d1 * 64 + lane) ^ ((d1 & 7) << 3)] = vv1[j];
    }
    __syncthreads();                        // staged data visible
    if (kbase > wqmin + 31) continue;       // tile fully masked for this wave (uniform)

    // QK^T (swapped): s0 = kv 0..31, s1 = kv 32..63
    f16v s0 = {}, s1 = {};
#pragma unroll
    for (int st = 0; st < 8; ++st) {
      int coff = st * 16 + hh * 8;
      bf8 a0 = __builtin_bit_cast(bf8, *(const us8*)&Ks[(l31 * 128 + coff) ^ swz]);
      bf8 a1 = __builtin_bit_cast(bf8, *(const us8*)&Ks[((l31 + 32) * 128 + coff) ^ swz]);
      s0 = mfma32(a0, qf[st], s0);
      s1 = mfma32(a1, qf[st], s1);
    }
    // causal mask (only the diagonal tile of this wave needs it)
    if (kbase + 63 > wqmin) {
#pragma unroll
      for (int r = 0; r < 16; ++r) {
        int kv = kbase + (r & 3) + 8 * (r >> 2) + 4 * hh;
        if (kv > q_g)      s0[r] = BNEG;
        if (kv + 32 > q_g) s1[r] = BNEG;
      }
    }
    // online softmax (log2 domain), per q-row = lane pair (l, l^32)
    float tmax = BNEG;
#pragma unroll
    for (int r = 0; r < 16; ++r) {
      tmax = fmaxf(tmax, s0[r]);
      tmax = fmaxf(tmax, s1[r]);
    }
    tmax = fmaxf(tmax, __shfl_xor(tmax, 32));
    float m_new = fmaxf(m_run, tmax);
    float fac = exp2f(m_run - m_new);       // per q=l31; exact 1.0 when max unchanged
    m_run = m_new;
    float psum = 0.f;
#pragma unroll
    for (int r = 0; r < 16; ++r) {
      s0[r] = exp2f(s0[r] - m_new); psum += s0[r];
      s1[r] = exp2f(s1[r] - m_new); psum += s1[r];
    }
    psum += __shfl_xor(psum, 32);
    l_run = l_run * fac + psum;
    // rescale yacc: its rows are q_local=crow(r,hh), NOT q=l31 -> broadcast fac
    if (!__all(fac == 1.0f)) {
      float facr[16];
#pragma unroll
      for (int r = 0; r < 16; ++r)
        facr[r] = __shfl(fac, (r & 3) + 8 * (r >> 2) + 4 * hh);
#pragma unroll
      for (int dc = 0; dc < 4; ++dc)
#pragma unroll
        for (int r = 0; r < 16; ++r) yacc[dc][r] *= facr[r];
    }

    // PV: rebuild P A-frags in-register (cvt_pk + cross-half exchange), then 16 MFMAs
#pragma unroll
    for (int st = 0; st < 4; ++st) {
      f16v sv = (st & 2) ? s1 : s0;
      const int rb = (st & 1) * 8;
      unsigned pkA = cvtpk(sv[rb + 0], sv[rb + 1]);
      unsigned pkB = cvtpk(sv[rb + 2], sv[rb + 3]);
      unsigned pkC = cvtpk(sv[rb + 4], sv[rb + 5]);
      unsigned pkD = cvtpk(sv[rb + 6], sv[rb + 7]);
      unsigned xA = __shfl_xor(pkA, 32);
      unsigned xB = __shfl_xor(pkB, 32);
      unsigned xC = __shfl_xor(pkC, 32);
      unsigned xD = __shfl_xor(pkD, 32);
      unsigned w0 = hh ? xC : pkA;    // A-frag j=0,1
      unsigned w1 = hh ? xD : pkB;    // j=2,3
      unsigned w2 = hh ? pkC : xA;    // j=4,5
      unsigned w3 = hh ? pkD : xB;    // j=6,7
      i4 wi = { (int)w0, (int)w1, (int)w2, (int)w3 };
      bf8 pf = __builtin_bit_cast(bf8, wi);
#pragma unroll
      for (int dc = 0; dc < 4; ++dc) {
        int d = dc * 32 + l31;
        bf8 vf = __builtin_bit_cast(bf8, *(const us8*)&Vt[(d * 64 + st * 16 + hh * 8) ^ swz]);
        yacc[dc] = mfma32(pf, vf, yacc[dc]);
      }
    }
  }
  // epilogue: broadcast 1/l to the C/D row layout, normalize, store bf16
  float inv_l = 1.0f / l_run;
  float il[16];
#pragma unroll
  for (int r = 0; r < 16; ++r)
    il[r] = __shfl(inv_l, (r & 3) + 8 * (r >> 2) + 4 * hh);
#pragma unroll
  for (int dc = 0; dc < 4; ++dc)
#pragma unroll
    for (int r = 0; r < 16; ++r) {
      int qrow = qb0 + w * 32 + (r & 3) + 8 * (r >> 2) + 4 * hh;
      Yb[(size_t)(b * T_SEQ + qrow) * 4096 + h * 128 + dc * 32 + l31] =
          f2bf(yacc[dc][r] * il[r]);
    }
}

extern "C" void kernel_launch(void* const* d_in, const int* in_sizes, int n_in,
                              void* d_out, int out_size, void* d_ws, size_t ws_size,
                              hipStream_t stream) {
  const float* x    = (const float*)d_in[0];
  // d_in[1] = freqs_cis (unused by the reference computation)
  const float* wqkv = (const float*)d_in[2];
  const float* wo   = (const float*)d_in[3];
  const float* cosp = (const float*)d_in[4];
  const float* sinp = (const float*)d_in[5];
  float* out = (float*)d_out;

  char* ws = (char*)d_ws;
  size_t o = 0;
  auto alloc = [&](size_t bytes) { void* p = ws + o; o += (bytes + 255) & ~(size_t)255; return p; };
  unsigned short* x_b    = (unsigned short*)alloc((size_t)M_TOK * DIM * 2);
  unsigned short* wqkv_b = (unsigned short*)alloc((size_t)EDIM * DIM * 2);
  unsigned short* wo_b   = (unsigned short*)alloc((size_t)DIM * DIM * 2);
  unsigned short* Qb     = (unsigned short*)alloc((size_t)M_TOK * 4096 * 2);
  unsigned short* Kb     = (unsigned short*)alloc((size_t)M_TOK * 1024 * 2);
  unsigned short* Vb     = (unsigned short*)alloc((size_t)M_TOK * 1024 * 2);
  unsigned short* Yb     = (unsigned short*)alloc((size_t)M_TOK * 4096 * 2);
  if (o > ws_size) return;  // workspace too small: fail visibly (zero output)

  k_f2bf<<<(M_TOK * DIM / 4 + 255) / 256, 256, 0, stream>>>(x, x_b, M_TOK * DIM / 4);
  k_f2bf<<<(EDIM * DIM / 4 + 255) / 256, 256, 0, stream>>>(wqkv, wqkv_b, EDIM * DIM / 4);
  k_f2bf<<<(DIM * DIM / 4 + 255) / 256, 256, 0, stream>>>(wo, wo_b, DIM * DIM / 4);

  k_gemm<0><<<dim3(EDIM / 128, M_TOK / 128), 256, 0, stream>>>(
      x_b, wqkv_b, M_TOK, EDIM, DIM, Qb, Kb, Vb, nullptr);

  k_rope<<<(M_TOK * NH * 16 + M_TOK * NKV * 16 + 255) / 256, 256, 0, stream>>>(
      Qb, Kb, cosp, sinp);

  k_attn<<<dim3(512, 1, 1), 512, 0, stream>>>(Qb, Kb, Vb, Yb);

  k_gemm<1><<<dim3(DIM / 128, M_TOK / 128), 256, 0, stream>>>(
      Yb, wo_b, M_TOK, DIM, DIM, nullptr, nullptr, nullptr, out);
}

// Round 4
// 529.111 us; speedup vs baseline: 2.0965x; 1.3075x over previous
//
#include <hip/hip_runtime.h>

#define T_SEQ 2048
#define NB    2
#define NH    32
#define NKV   8
#define HD    128
#define DIM   4096
#define EDIM  6144
#define M_TOK 4096   // NB*T_SEQ

typedef __bf16          bf8  __attribute__((ext_vector_type(8)));
typedef unsigned short  us8  __attribute__((ext_vector_type(8)));
typedef float           f4   __attribute__((ext_vector_type(4)));
typedef float           f16v __attribute__((ext_vector_type(16)));
typedef int             i4   __attribute__((ext_vector_type(4)));

__device__ inline unsigned short f2bf(float f) {
  unsigned int u = __builtin_bit_cast(unsigned int, f);
  u += 0x7FFF + ((u >> 16) & 1);              // round-to-nearest-even
  return (unsigned short)(u >> 16);
}
__device__ inline float bf2f(unsigned short h) {
  unsigned int u = ((unsigned int)h) << 16;
  return __builtin_bit_cast(float, u);
}
__device__ inline void gl_lds16(const void* g, void* l) {
  __builtin_amdgcn_global_load_lds(
      (const __attribute__((address_space(1))) unsigned int*)g,
      (__attribute__((address_space(3))) unsigned int*)l, 16, 0, 0);
}
__device__ inline f4 mfma16(bf8 a, bf8 b, f4 c) {
  return __builtin_amdgcn_mfma_f32_16x16x32_bf16(a, b, c, 0, 0, 0);
}
__device__ inline f16v mfma32(bf8 a, bf8 b, f16v c) {
  return __builtin_amdgcn_mfma_f32_32x32x16_bf16(a, b, c, 0, 0, 0);
}
__device__ inline unsigned cvtpk(float lo, float hi) {
  unsigned r;
  asm("v_cvt_pk_bf16_f32 %0, %1, %2" : "=v"(r) : "v"(lo), "v"(hi));
  return r;
}

// ---------------- f32 -> bf16 conversion ----------------
__global__ void k_f2bf(const float* __restrict__ in, unsigned short* __restrict__ out, int n4) {
  int i = blockIdx.x * blockDim.x + threadIdx.x;
  if (i >= n4) return;
  f4 v = *(const f4*)(in + (size_t)i * 4);
  unsigned long long pack =
      (unsigned long long)f2bf(v[0]) |
      ((unsigned long long)f2bf(v[1]) << 16) |
      ((unsigned long long)f2bf(v[2]) << 32) |
      ((unsigned long long)f2bf(v[3]) << 48);
  *(unsigned long long*)(out + (size_t)i * 4) = pack;
}

// =============== 256x256 8-phase GEMM: C[m,n] = sum_k A[m,k]*B[n,k] ===============
// 8 waves (2M x 4N), BK=64, double-buffered 128KiB LDS, XOR-swizzled (T2),
// 8-phase counted-vmcnt schedule (T3+T4), setprio around MFMA (T5), XCD swizzle (T1).
// Wave w: wr=w>>2, wc=w&3. Per-wave C = rows {wr*64+[0,64)} u {128+wr*64+[0,64)}
//                               x cols {wc*32+[0,32)} u {128+wc*32+[0,32)}.
// Quadrant phases per K-tile: (m0n0),(m0n1),(m1n1),(m1n0) -> one LDS half dies per
// phase; stage 1 half-tile/phase (2 gl_lds) into the region that died last phase.
// Stage->first-read slack = 4 phases = 3 half-tiles = vmcnt(6) at phases 4 & 8.

#define MFMA_Q(a0, b0, AF, BF)                                        \
  __builtin_amdgcn_s_setprio(1);                                      \
  _Pragma("unroll") for (int mi = 0; mi < 4; ++mi)                    \
  _Pragma("unroll") for (int ni = 0; ni < 2; ++ni)                    \
  _Pragma("unroll") for (int kk = 0; kk < 2; ++kk)                    \
      acc[(a0) + mi][(b0) + ni] =                                     \
          mfma16(AF[mi][kk], BF[ni][kk], acc[(a0) + mi][(b0) + ni]);  \
  __builtin_amdgcn_s_setprio(0);

#define RD_A(buf, mh)                                                 \
  _Pragma("unroll") for (int mi = 0; mi < 4; ++mi)                    \
  _Pragma("unroll") for (int kk = 0; kk < 2; ++kk)                    \
      af[mi][kk] = rdA(buf, mh, mi, kk);

#define RD_B(buf, nh, BF)                                             \
  _Pragma("unroll") for (int ni = 0; ni < 2; ++ni)                    \
  _Pragma("unroll") for (int kk = 0; kk < 2; ++kk)                    \
      BF[ni][kk] = rdB(buf, nh, ni, kk);

template <int MODE>
__global__ __launch_bounds__(512, 2)
void k_gemm256(const unsigned short* __restrict__ A, const unsigned short* __restrict__ Bm,
               int M, int N, int K,
               unsigned short* __restrict__ oQ, unsigned short* __restrict__ oK,
               unsigned short* __restrict__ oV, float* __restrict__ oF) {
  __shared__ unsigned short As[2][16384];   // [buf][row*64 + swz-col], 256 rows
  __shared__ unsigned short Bs[2][16384];
  const int nbx = N >> 8;
  const int nwg = nbx * (M >> 8);
  {
  }
  const int n0 = blockIdx.x;
  const int q8 = nwg >> 3, r8 = nwg & 7;
  const int xcd = n0 & 7, ix = n0 >> 3;
  const int swzb = (xcd < r8 ? xcd * (q8 + 1) : r8 * (q8 + 1) + (xcd - r8) * q8) + ix;
  const int bn = swzb % nbx, bm = swzb / nbx;
  const int t = threadIdx.x;
  const int lane = t & 63, w = t >> 6;
  const int wr = w >> 2, wc = w & 3;
  const int l15 = lane & 15, lhi = lane >> 4;
  const int KT = K >> 6;                    // # K-tiles (even: K=4096 -> 64)
  const int NI = KT >> 1;

  f4 acc[8][4] = {};

  const int tt0 = t * 8;
  auto stA = [&](int buf, int half, int tile) {
    if (tile >= KT) return;
    const unsigned short* gp = A + (size_t)(bm * 256 + half * 128) * K + tile * 64;
#pragma unroll
    for (int j = 0; j < 2; ++j) {
      int e = j * 4096 + tt0;               // elem within 128x64 half
      int rl = e >> 6;
      int cs = (e & 63) ^ ((rl & 7) << 3);  // pre-swizzled source col
      gl_lds16(gp + (size_t)rl * K + cs, &As[buf][half * 8192 + e]);
    }
  };
  auto stB = [&](int buf, int half, int tile) {
    if (tile >= KT) return;
    const unsigned short* gp = Bm + (size_t)(bn * 256 + half * 128) * K + tile * 64;
#pragma unroll
    for (int j = 0; j < 2; ++j) {
      int e = j * 4096 + tt0;
      int rl = e >> 6;
      int cs = (e & 63) ^ ((rl & 7) << 3);
      gl_lds16(gp + (size_t)rl * K + cs, &Bs[buf][half * 8192 + e]);
    }
  };
  auto rdA = [&](int buf, int mh, int mi, int kk) -> bf8 {
    int row = mh * 128 + wr * 64 + mi * 16 + l15;
    int col = (lhi * 8 + kk * 32) ^ ((row & 7) << 3);
    return __builtin_bit_cast(bf8, *(const us8*)&As[buf][row * 64 + col]);
  };
  auto rdB = [&](int buf, int nh, int ni, int kk) -> bf8 {
    int row = nh * 128 + wc * 32 + ni * 16 + l15;
    int col = (lhi * 8 + kk * 32) ^ ((row & 7) << 3);
    return __builtin_bit_cast(bf8, *(const us8*)&Bs[buf][row * 64 + col]);
  };
  auto bar = [&]() {
    asm volatile("" ::: "memory");
    __builtin_amdgcn_s_barrier();
    asm volatile("" ::: "memory");
  };
  auto lgkm0 = [&]() {
    asm volatile("s_waitcnt lgkmcnt(0)" ::: "memory");
    __builtin_amdgcn_sched_barrier(0);
  };

  // prologue: tile0 fully (8 loads), tile1 {A-h0, B-h1, A-h1} (6 loads)
  stA(0, 0, 0); stB(0, 1, 0); stA(0, 1, 0); stB(0, 0, 0);
  stA(1, 0, 1); stB(1, 1, 1); stA(1, 1, 1);
  asm volatile("s_waitcnt vmcnt(6)" ::: "memory");   // tile0 landed; tile1's 3 in flight
  bar();

  for (int i = 0; i < NI; ++i) {
    const int t2 = 2 * i + 2, t3 = 2 * i + 3;
    bf8 af[4][2], bf0[2][2], bf1[2][2];
    // ---- tile 2i (buf0) ----
    // ph1
    RD_A(0, 0); RD_B(0, 0, bf0);
    stB(1, 0, 2 * i + 1);                   // B-h0(buf1) <- tile 2i+1
    bar(); lgkm0();
    MFMA_Q(0, 0, af, bf0);
    bar();
    // ph2
    RD_B(0, 1, bf1);
    stA(0, 0, t2);
    bar(); lgkm0();
    MFMA_Q(0, 2, af, bf1);
    bar();
    // ph3
    RD_A(0, 1);
    stB(0, 1, t2);
    bar(); lgkm0();
    MFMA_Q(4, 2, af, bf1);
    bar();
    // ph4
    RD_B(0, 0, bf0);
    stA(0, 1, t2);
    bar(); lgkm0();
    MFMA_Q(4, 0, af, bf0);
    if (i + 1 < NI) { asm volatile("s_waitcnt vmcnt(6)" ::: "memory"); }
    else            { asm volatile("s_waitcnt vmcnt(0)" ::: "memory"); }
    bar();
    // ---- tile 2i+1 (buf1) ----
    // ph5
    RD_A(1, 0); RD_B(1, 0, bf0);
    stB(0, 0, t2);
    bar(); lgkm0();
    MFMA_Q(0, 0, af, bf0);
    bar();
    // ph6
    RD_B(1, 1, bf1);
    stA(1, 0, t3);
    bar(); lgkm0();
    MFMA_Q(0, 2, af, bf1);
    bar();
    // ph7
    RD_A(1, 1);
    stB(1, 1, t3);
    bar(); lgkm0();
    MFMA_Q(4, 2, af, bf1);
    bar();
    // ph8
    RD_B(1, 0, bf0);
    stA(1, 1, t3);
    bar(); lgkm0();
    MFMA_Q(4, 0, af, bf0);
    if (i + 1 < NI) { asm volatile("s_waitcnt vmcnt(6)" ::: "memory"); }
    bar();
  }

  // epilogue
  const int rb0 = bm * 256 + wr * 64 + lhi * 4;
  const int cb0 = bn * 256 + wc * 32 + l15;
  if (MODE == 0) {
    unsigned short* op; int ldo, coff;
    const int cbase = bn * 256;
    if (cbase < 4096)      { op = oQ; ldo = 4096; coff = cb0; }
    else if (cbase < 5120) { op = oK; ldo = 1024; coff = cb0 - 4096; }
    else                   { op = oV; ldo = 1024; coff = cb0 - 5120; }
#pragma unroll
    for (int ai = 0; ai < 8; ++ai)
#pragma unroll
      for (int bj = 0; bj < 4; ++bj)
#pragma unroll
        for (int rr = 0; rr < 4; ++rr) {
          int row = rb0 + (ai >> 2) * 128 + (ai & 3) * 16 + rr;
          int col = coff + (bj >> 1) * 128 + (bj & 1) * 16;
          op[(size_t)row * ldo + col] = f2bf(acc[ai][bj][rr]);
        }
  } else {
#pragma unroll
    for (int ai = 0; ai < 8; ++ai)
#pragma unroll
      for (int bj = 0; bj < 4; ++bj)
#pragma unroll
        for (int rr = 0; rr < 4; ++rr) {
          int row = rb0 + (ai >> 2) * 128 + (ai & 3) * 16 + rr;
          int col = cb0 + (bj >> 1) * 128 + (bj & 1) * 16;
          oF[(size_t)row * N + col] = acc[ai][bj][rr];
        }
  }
}

// ---------------- RoPE in-place; Q additionally scaled by SCALE*log2(e) ----------------
__global__ void k_rope(unsigned short* __restrict__ Qb, unsigned short* __restrict__ Kb,
                       const float* __restrict__ cosp, const float* __restrict__ sinp) {
  const float QSCALE = (float)(0.08838834764831845 * 1.4426950408889634);
  int idx = blockIdx.x * blockDim.x + threadIdx.x;
  const int nq = M_TOK * NH * 16;   // each thread: 4 pairs = 8 bf16
  const int nk = M_TOK * NKV * 16;
  unsigned short* p; int tpos, pg; float sc;
  if (idx < nq) {
    int m = idx >> 9;
    int r = idx & 511;
    int h = r >> 4; pg = r & 15;
    tpos = m & (T_SEQ - 1);
    p = Qb + (size_t)m * 4096 + h * 128 + pg * 8;
    sc = QSCALE;
  } else {
    idx -= nq;
    if (idx >= nk) return;
    int m = idx >> 7;
    int r = idx & 127;
    int h = r >> 4; pg = r & 15;
    tpos = m & (T_SEQ - 1);
    p = Kb + (size_t)m * 1024 + h * 128 + pg * 8;
    sc = 1.0f;
  }
  us8 v = *(const us8*)p;
  f4 c = *(const f4*)(cosp + tpos * 64 + pg * 4);
  f4 s = *(const f4*)(sinp + tpos * 64 + pg * 4);
  us8 o;
#pragma unroll
  for (int j = 0; j < 4; ++j) {
    float cs = c[j] * sc, ss = s[j] * sc;
    float tr = bf2f(v[2 * j]), ti = bf2f(v[2 * j + 1]);
    o[2 * j]     = f2bf(tr * cs - ti * ss);
    o[2 * j + 1] = f2bf(tr * ss + ti * cs);
  }
  *(us8*)p = o;
}

// ---------------- Flash attention: 8 waves x 32 q-rows, 32x32x16 MFMA ----------------
// Swapped QK^T: S^T[kv][q] = mfma(A=K, B=Q). C/D layout: col(=q)=lane&31,
// row(=kv)=(reg&3)+8*(reg>>2)+4*(lane>>5). Per-q softmax stats live at lane q=l31;
// the PV accumulator's rows are q_local=crow(r,hh), so BOTH the per-tile rescale
// factor and the final 1/l are broadcast via shfl to the C/D row layout.
__global__ __launch_bounds__(512, 2)
void k_attn(const unsigned short* __restrict__ Qb, const unsigned short* __restrict__ Kb,
            const unsigned short* __restrict__ Vb, unsigned short* __restrict__ Yb) {
  __shared__ unsigned short Ks[64 * 128];
  __shared__ unsigned short Vt[128 * 64];
  const int idx = blockIdx.x;
  const int qblk = 7 - (idx >> 6);          // heavy blocks dispatched first
  const int h = (idx & 63) >> 1;
  const int b = idx & 1;
  const int kvh = h >> 2;
  const int t = threadIdx.x;
  const int lane = t & 63, w = t >> 6;
  const int l31 = lane & 31, hh = lane >> 5;
  const int qb0 = qblk * 256;
  const int NT = (qblk + 1) * 4;
  const int wqmin = qb0 + w * 32;
  const int q_g = wqmin + l31;              // this lane's q row (S/P layout)
  const float BNEG = -1.0e30f;

  bf8 qf[8];
  {
    const unsigned short* qp = Qb + (size_t)(b * T_SEQ + q_g) * 4096 + h * 128 + hh * 8;
#pragma unroll
    for (int st = 0; st < 8; ++st) qf[st] = __builtin_bit_cast(bf8, *(const us8*)(qp + st * 16));
  }
  const int swz = (l31 & 7) << 3;           // element-unit XOR swizzle (bits 3..5)
  float m_run = BNEG, l_run = 0.f;
  f16v yacc[4] = {};

  const int eo0 = t * 8;
  for (int kt = 0; kt < NT; ++kt) {
    const int kbase = kt * 64;
    const unsigned short* vp = Vb + (size_t)(b * T_SEQ + kbase + lane) * 1024 + kvh * 128 + w * 8;
    us8 vv0 = *(const us8*)vp;
    us8 vv1 = *(const us8*)(vp + 64);
    __syncthreads();                        // prev tile's LDS reads done
#pragma unroll
    for (int i = 0; i < 2; ++i) {
      int eo = i * 4096 + eo0;
      int row = eo >> 7;
      int colL = (eo & 127) ^ ((row & 7) << 3);
      gl_lds16(Kb + (size_t)(b * T_SEQ + kbase + row) * 1024 + kvh * 128 + colL, &Ks[eo]);
    }
#pragma unroll
    for (int j = 0; j < 8; ++j) {
      int d0 = w * 8 + j;
      Vt[(d0 * 64 + lane) ^ ((d0 & 7) << 3)] = vv0[j];
      int d1 = d0 + 64;
      Vt[(d1 * 64 + lane) ^ ((d1 & 7) << 3)] = vv1[j];
    }
    __syncthreads();                        // staged data visible
    if (kbase > wqmin + 31) continue;       // tile fully masked for this wave (uniform)

    f16v s0 = {}, s1 = {};
#pragma unroll
    for (int st = 0; st < 8; ++st) {
      int coff = st * 16 + hh * 8;
      bf8 a0 = __builtin_bit_cast(bf8, *(const us8*)&Ks[(l31 * 128 + coff) ^ swz]);
      bf8 a1 = __builtin_bit_cast(bf8, *(const us8*)&Ks[((l31 + 32) * 128 + coff) ^ swz]);
      s0 = mfma32(a0, qf[st], s0);
      s1 = mfma32(a1, qf[st], s1);
    }
    if (kbase + 63 > wqmin) {
#pragma unroll
      for (int r = 0; r < 16; ++r) {
        int kv = kbase + (r & 3) + 8 * (r >> 2) + 4 * hh;
        if (kv > q_g)      s0[r] = BNEG;
        if (kv + 32 > q_g) s1[r] = BNEG;
      }
    }
    float tmax = BNEG;
#pragma unroll
    for (int r = 0; r < 16; ++r) {
      tmax = fmaxf(tmax, s0[r]);
      tmax = fmaxf(tmax, s1[r]);
    }
    tmax = fmaxf(tmax, __shfl_xor(tmax, 32));
    float m_new = fmaxf(m_run, tmax);
    float fac = exp2f(m_run - m_new);       // per q=l31; exact 1.0 when max unchanged
    m_run = m_new;
    float psum = 0.f;
#pragma unroll
    for (int r = 0; r < 16; ++r) {
      s0[r] = exp2f(s0[r] - m_new); psum += s0[r];
      s1[r] = exp2f(s1[r] - m_new); psum += s1[r];
    }
    psum += __shfl_xor(psum, 32);
    l_run = l_run * fac + psum;
    if (!__all(fac == 1.0f)) {
      float facr[16];
#pragma unroll
      for (int r = 0; r < 16; ++r)
        facr[r] = __shfl(fac, (r & 3) + 8 * (r >> 2) + 4 * hh);
#pragma unroll
      for (int dc = 0; dc < 4; ++dc)
#pragma unroll
        for (int r = 0; r < 16; ++r) yacc[dc][r] *= facr[r];
    }
#pragma unroll
    for (int st = 0; st < 4; ++st) {
      f16v sv = (st & 2) ? s1 : s0;
      const int rb = (st & 1) * 8;
      unsigned pkA = cvtpk(sv[rb + 0], sv[rb + 1]);
      unsigned pkB = cvtpk(sv[rb + 2], sv[rb + 3]);
      unsigned pkC = cvtpk(sv[rb + 4], sv[rb + 5]);
      unsigned pkD = cvtpk(sv[rb + 6], sv[rb + 7]);
      unsigned xA = __shfl_xor(pkA, 32);
      unsigned xB = __shfl_xor(pkB, 32);
      unsigned xC = __shfl_xor(pkC, 32);
      unsigned xD = __shfl_xor(pkD, 32);
      unsigned w0 = hh ? xC : pkA;
      unsigned w1 = hh ? xD : pkB;
      unsigned w2 = hh ? pkC : xA;
      unsigned w3 = hh ? pkD : xB;
      i4 wi = { (int)w0, (int)w1, (int)w2, (int)w3 };
      bf8 pf = __builtin_bit_cast(bf8, wi);
#pragma unroll
      for (int dc = 0; dc < 4; ++dc) {
        int d = dc * 32 + l31;
        bf8 vf = __builtin_bit_cast(bf8, *(const us8*)&Vt[(d * 64 + st * 16 + hh * 8) ^ swz]);
        yacc[dc] = mfma32(pf, vf, yacc[dc]);
      }
    }
  }
  float inv_l = 1.0f / l_run;
  float il[16];
#pragma unroll
  for (int r = 0; r < 16; ++r)
    il[r] = __shfl(inv_l, (r & 3) + 8 * (r >> 2) + 4 * hh);
#pragma unroll
  for (int dc = 0; dc < 4; ++dc)
#pragma unroll
    for (int r = 0; r < 16; ++r) {
      int qrow = qb0 + w * 32 + (r & 3) + 8 * (r >> 2) + 4 * hh;
      Yb[(size_t)(b * T_SEQ + qrow) * 4096 + h * 128 + dc * 32 + l31] =
          f2bf(yacc[dc][r] * il[r]);
    }
}

extern "C" void kernel_launch(void* const* d_in, const int* in_sizes, int n_in,
                              void* d_out, int out_size, void* d_ws, size_t ws_size,
                              hipStream_t stream) {
  const float* x    = (const float*)d_in[0];
  // d_in[1] = freqs_cis (unused by the reference computation)
  const float* wqkv = (const float*)d_in[2];
  const float* wo   = (const float*)d_in[3];
  const float* cosp = (const float*)d_in[4];
  const float* sinp = (const float*)d_in[5];
  float* out = (float*)d_out;

  char* ws = (char*)d_ws;
  size_t o = 0;
  auto alloc = [&](size_t bytes) { void* p = ws + o; o += (bytes + 255) & ~(size_t)255; return p; };
  unsigned short* x_b    = (unsigned short*)alloc((size_t)M_TOK * DIM * 2);
  unsigned short* wqkv_b = (unsigned short*)alloc((size_t)EDIM * DIM * 2);
  unsigned short* wo_b   = (unsigned short*)alloc((size_t)DIM * DIM * 2);
  unsigned short* Qb     = (unsigned short*)alloc((size_t)M_TOK * 4096 * 2);
  unsigned short* Kb     = (unsigned short*)alloc((size_t)M_TOK * 1024 * 2);
  unsigned short* Vb     = (unsigned short*)alloc((size_t)M_TOK * 1024 * 2);
  unsigned short* Yb     = (unsigned short*)alloc((size_t)M_TOK * 4096 * 2);
  if (o > ws_size) return;  // workspace too small: fail visibly (zero output)

  k_f2bf<<<(M_TOK * DIM / 4 + 255) / 256, 256, 0, stream>>>(x, x_b, M_TOK * DIM / 4);
  k_f2bf<<<(EDIM * DIM / 4 + 255) / 256, 256, 0, stream>>>(wqkv, wqkv_b, EDIM * DIM / 4);
  k_f2bf<<<(DIM * DIM / 4 + 255) / 256, 256, 0, stream>>>(wo, wo_b, DIM * DIM / 4);

  k_gemm256<0><<<dim3((EDIM / 256) * (M_TOK / 256)), 512, 0, stream>>>(
      x_b, wqkv_b, M_TOK, EDIM, DIM, Qb, Kb, Vb, nullptr);

  k_rope<<<(M_TOK * NH * 16 + M_TOK * NKV * 16 + 255) / 256, 256, 0, stream>>>(
      Qb, Kb, cosp, sinp);

  k_attn<<<dim3(512, 1, 1), 512, 0, stream>>>(Qb, Kb, Vb, Yb);

  k_gemm256<1><<<dim3((DIM / 256) * (M_TOK / 256)), 512, 0, stream>>>(
      Yb, wo_b, M_TOK, DIM, DIM, nullptr, nullptr, nullptr, out);
}